// Round 7
// baseline (524.654 us; speedup 1.0000x reference)
//
#include <hip/hip_runtime.h>

#define T_LEN  16384
#define LTAG   64
#define F_PER  14
#define NCHUNK 256
#define CHUNK  64
#define BOS_ID 0
#define EOS_ID 1
#define NREG   10
#define REGSZ  500000      // 10 x 500000 = 5,000,000 = NB_FEATURES ; 2 MB per region

typedef __attribute__((ext_vector_type(4))) float f4;

// workspace layout (bytes)
static constexpr size_t EM_OFF  = 0;                                   // float[T*64]  4 MB
static constexpr size_t P_OFF   = EM_OFF + (size_t)T_LEN * 64 * 4;     // float[256*4096] 4 MB
static constexpr size_t AB_OFF  = P_OFF + (size_t)NCHUNK * 4096 * 4;   // double[257*64]
static constexpr size_t BP_OFF  = AB_OFF + (size_t)257 * 64 * 8;       // uchar[T*64] 1 MB
static constexpr size_t G_OFF   = BP_OFF + (size_t)T_LEN * 64;         // uchar[256*64]
static constexpr size_t BT_OFF  = G_OFF + (size_t)NCHUNK * 64;         // int[257]
static constexpr size_t U_OFF   = BT_OFF + 4096;                       // float[256*256] u per strip
static constexpr size_t V_OFF   = U_OFF + (size_t)NCHUNK * 256 * 4;    // float[256*64]  v per strip
static constexpr size_t FLG_OFF = V_OFF + (size_t)NCHUNK * 64 * 4;     // uchar[256*4]

// ---------------------------------------------------------------------------
// K1: emissions  em[t,l] = sum_f w[feat[t,l,f]]  (fp32)
// Ballot-sorted region-bucket gather. Block = 64 threads = 1 wave; each block
// owns 64 (t,l) cells = 896 indices. Counting-sort them into LDS buckets by
// 2 MB table region (ballot histogram + mbcnt prefix — no atomics), then
// sweep regions in order with DENSE gathers (14 fully-active vmem instr
// instead of 140 sparse predicated ones), accumulating per-owner via
// LDS float atomics. Region order across co-resident blocks keeps the
// active 2 MB window hot in each XCD's L2.
// ---------------------------------------------------------------------------
__global__ __launch_bounds__(64) void k_emissions(
    const int* __restrict__ idx, const float* __restrict__ w, float* __restrict__ em)
{
    __shared__ unsigned ebuf[64 * F_PER];   // 896 packed (owner<<23 | idx)
    __shared__ float    sacc[64];
    const int tid   = threadIdx.x;
    const int cell0 = blockIdx.x * 64;
    const int* p = idx + (size_t)cell0 * F_PER + (size_t)tid * F_PER;
    int id[F_PER];
#pragma unroll
    for (int f = 0; f < F_PER; ++f) id[f] = __builtin_nontemporal_load(p + f);
    sacc[tid] = 0.f;

    unsigned rg[F_PER];
#pragma unroll
    for (int f = 0; f < F_PER; ++f) rg[f] = (unsigned)id[f] / (unsigned)REGSZ;

    // pass 1: block histogram via ballots (all values wave-uniform)
    unsigned cnt[NREG];
#pragma unroll
    for (int r = 0; r < NREG; ++r) cnt[r] = 0;
#pragma unroll
    for (int f = 0; f < F_PER; ++f) {
#pragma unroll
        for (int r = 0; r < NREG; ++r) {
            const unsigned long long m = __ballot(rg[f] == (unsigned)r);
            cnt[r] += (unsigned)__popcll(m);
        }
    }
    unsigned start[NREG + 1];
    start[0] = 0;
#pragma unroll
    for (int r = 0; r < NREG; ++r) start[r + 1] = start[r] + cnt[r];

    // pass 2: place entries (prefix within ballot via mbcnt)
    unsigned b[NREG];
#pragma unroll
    for (int r = 0; r < NREG; ++r) b[r] = start[r];
#pragma unroll
    for (int f = 0; f < F_PER; ++f) {
        unsigned pos = 0;
#pragma unroll
        for (int r = 0; r < NREG; ++r) {
            const unsigned long long m = __ballot(rg[f] == (unsigned)r);
            if (rg[f] == (unsigned)r) {
                const unsigned pre = __builtin_amdgcn_mbcnt_hi(
                    (unsigned)(m >> 32),
                    __builtin_amdgcn_mbcnt_lo((unsigned)m, 0u));
                pos = b[r] + pre;
            }
            b[r] += (unsigned)__popcll(m);
        }
        ebuf[pos] = (unsigned)id[f] | ((unsigned)tid << 23);
    }
    __syncthreads();

    // region sweep: dense gathers, LDS accumulate per owner
    for (int r = 0; r < NREG; ++r) {
        const unsigned e1 = start[r + 1];
        for (unsigned e = start[r] + tid; e < e1; e += 64) {
            const unsigned u = ebuf[e];
            const float val = w[u & 0x7FFFFFu];
            atomicAdd(&sacc[u >> 23], val);
        }
    }
    __syncthreads();
    em[cell0 + tid] = sacc[tid];
}

// ---------------------------------------------------------------------------
// K2: phase 1 — per-chunk (max,+) transfer matrices, fp32, column-split,
// with max-plus rank-1 collapse early-exit. Collapsed strips emit (u,v,flag=1)
// instead of the full 16-column strip of Pg; non-collapsed emit Pg + flag=0.
// ---------------------------------------------------------------------------
__global__ __launch_bounds__(64) void k_phase1(
    const float* __restrict__ trans, const float* __restrict__ em, float* __restrict__ Pg,
    float* __restrict__ U, float* __restrict__ V, unsigned char* __restrict__ flags)
{
    __shared__ float sT[4096];      // 16 KB  sT[k*64+j] = T[k][j]
    __shared__ float sP[64 * 16];   // 4 KB   sP[j*16+i] = P[j][ib+i]
    __shared__ float sEm[64 * 64];  // 16 KB  emissions for this chunk
    __shared__ float su[64];
    __shared__ float sv[16];
    __shared__ float spart[256];
    const int bb  = blockIdx.x;
    const int c   = bb >> 2;
    const int st  = bb & 3;
    const int ib  = st << 4;
    const int tid = threadIdx.x;
    const int i0  = (tid & 3) << 2;
    const int j0  = (tid >> 2) << 2;
    const int t0  = c << 6;
    int nsteps = (T_LEN - 1) - t0; if (nsteps > CHUNK) nsteps = CHUNK;
    for (int x = tid; x < 4096; x += 64) sT[x] = trans[x];
    {   // stage emissions em[t0+1 .. t0+nsteps][:] -> sEm[s*64+j]
        const float* eg = em + (size_t)(t0 + 1) * 64;
        for (int x = tid * 4; x < nsteps * 64; x += 256)
            *(f4*)(sEm + x) = *(const f4*)(eg + x);
    }
    __syncthreads();

    float acc[4][4];
    // init step s=0: P[j][i] = e0[j] + T[ib+i][j]
    {
        const f4 e = *(const f4*)(sEm + j0);
#pragma unroll
        for (int jj = 0; jj < 4; ++jj) {
#pragma unroll
            for (int ii = 0; ii < 4; ++ii)
                acc[jj][ii] = e[jj] + sT[(ib + i0 + ii) * 64 + (j0 + jj)];
            f4 row = { acc[jj][0], acc[jj][1], acc[jj][2], acc[jj][3] };
            *(f4*)(sP + (j0 + jj) * 16 + i0) = row;
        }
    }
    __syncthreads();

    int coll = -1;
    for (int s = 1; s < nsteps; ++s) {
        const f4 e = *(const f4*)(sEm + s * 64 + j0);
#pragma unroll
        for (int jj = 0; jj < 4; ++jj)
#pragma unroll
            for (int ii = 0; ii < 4; ++ii) acc[jj][ii] = -3.0e38f;
#pragma unroll 8
        for (int k = 0; k < 64; k += 2) {
            const f4 ta = *(const f4*)(sT + k * 64 + j0);
            const f4 tb = *(const f4*)(sT + (k + 1) * 64 + j0);
            const f4 pa = *(const f4*)(sP + k * 16 + i0);
            const f4 pb = *(const f4*)(sP + (k + 1) * 16 + i0);
#pragma unroll
            for (int jj = 0; jj < 4; ++jj)
#pragma unroll
                for (int ii = 0; ii < 4; ++ii)
                    acc[jj][ii] = fmaxf(fmaxf(acc[jj][ii], ta[jj] + pa[ii]),
                                        tb[jj] + pb[ii]);
        }
        __syncthreads();
#pragma unroll
        for (int jj = 0; jj < 4; ++jj) {
            f4 row = { acc[jj][0] + e[jj], acc[jj][1] + e[jj],
                       acc[jj][2] + e[jj], acc[jj][3] + e[jj] };
            *(f4*)(sP + (j0 + jj) * 16 + i0) = row;
        }
        __syncthreads();
        // rank-1 check: (P[j][i]-P[j][0]) must equal (P[0][i]-P[0][0]) for all i,j
        {
            const f4 refi = *(const f4*)(sP + i0);   // row j=0, this thread's cols
            const float ref0 = sP[0];
            float dev = 0.f;
#pragma unroll
            for (int jj = 0; jj < 4; ++jj) {
                const float cj = sP[(j0 + jj) * 16];
#pragma unroll
                for (int ii = 0; ii < 4; ++ii) {
                    const float val = acc[jj][ii] + e[jj];
                    dev = fmaxf(dev, fabsf((val - cj) - (refi[ii] - ref0)));
                }
            }
            if (__ballot(dev <= 1.0e-2f) == ~0ULL) { coll = s; break; }
        }
    }

    if (coll >= 0) {
        // P = u + v ; run cheap vector recursion on u for remaining steps
        if (tid < 16) sv[tid] = sP[tid] - sP[0];
        su[tid] = sP[tid * 16];
        __syncthreads();
        const int kq = tid & 3;            // k-group (16 k's)
        const int jq = (tid >> 2) << 2;    // 4 j's
        for (int s = coll + 1; s < nsteps; ++s) {
            float pm0 = -3.0e38f, pm1 = -3.0e38f, pm2 = -3.0e38f, pm3 = -3.0e38f;
#pragma unroll
            for (int kk = 0; kk < 16; ++kk) {
                const int k = (kq << 4) + kk;
                const float uk = su[k];
                const f4 ta = *(const f4*)(sT + k * 64 + jq);
                pm0 = fmaxf(pm0, ta[0] + uk);
                pm1 = fmaxf(pm1, ta[1] + uk);
                pm2 = fmaxf(pm2, ta[2] + uk);
                pm3 = fmaxf(pm3, ta[3] + uk);
            }
            spart[(jq + 0) * 4 + kq] = pm0;
            spart[(jq + 1) * 4 + kq] = pm1;
            spart[(jq + 2) * 4 + kq] = pm2;
            spart[(jq + 3) * 4 + kq] = pm3;
            __syncthreads();                       // spart visible; su reads done
            const f4 pr = *(const f4*)(spart + tid * 4);
            const float un = sEm[s * 64 + tid] +
                fmaxf(fmaxf(pr[0], pr[1]), fmaxf(pr[2], pr[3]));
            su[tid] = un;
            __syncthreads();                       // su visible; spart reads done
        }
        // rank-1 emit: u (64), v (16), flag=1 — no Pg write
        U[(size_t)c * 256 + tid * 4 + st] = su[tid];
        if (tid < 16) V[(size_t)c * 64 + ib + tid] = sv[tid];
        if (tid == 0) flags[c * 4 + st] = 1;
        return;
    }

    // matrix-mode writeout + flag=0
#pragma unroll
    for (int jj = 0; jj < 4; ++jj) {
        const f4 row = *(const f4*)(sP + (j0 + jj) * 16 + i0);
        *(f4*)(Pg + (size_t)c * 4096 + (j0 + jj) * 64 + ib + i0) = row;
    }
    if (tid == 0) flags[c * 4 + st] = 0;
}

// ---------------------------------------------------------------------------
// K3: phase 2 — sequential scan over rank-1 strips, single wave, barrier-free,
// with depth-1 software prefetch of (flags,u,v) so the c+1 loads overlap the
// c shuffle chain instead of serializing behind it.
// ---------------------------------------------------------------------------
__global__ __launch_bounds__(64) void k_phase2(
    const float* __restrict__ trans, const float* __restrict__ em,
    const float* __restrict__ Pg, const float* __restrict__ U,
    const float* __restrict__ V, const unsigned char* __restrict__ flags,
    double* __restrict__ aB)
{
    const int j = threadIdx.x;
    const double a0 = (double)trans[BOS_ID * 64 + j] + (double)em[j];
    aB[j] = a0;
    double base = __shfl(a0, 0);
    float a = (float)(a0 - base);

    unsigned fl_n = *(const unsigned*)flags;
    f4       u_n  = *(const f4*)(U + j * 4);
    float    v_n  = V[j];

    for (int c = 0; c < NCHUNK; ++c) {
        const unsigned fl = fl_n;
        const f4       u  = u_n;
        const float    v  = v_n;
        if (c + 1 < NCHUNK) {
            fl_n = *(const unsigned*)(flags + 4 * (c + 1));
            u_n  = *(const f4*)(U + (size_t)(c + 1) * 256 + j * 4);
            v_n  = V[(size_t)(c + 1) * 64 + j];
        }
        // segmented 16-lane max of (v + a)
        float x = v + a;
        x = fmaxf(x, __shfl_xor(x, 1));
        x = fmaxf(x, __shfl_xor(x, 2));
        x = fmaxf(x, __shfl_xor(x, 4));
        x = fmaxf(x, __shfl_xor(x, 8));
        const unsigned xu = __float_as_uint(x);
        const float m0 = __uint_as_float(__builtin_amdgcn_readlane(xu, 0));
        const float m1 = __uint_as_float(__builtin_amdgcn_readlane(xu, 16));
        const float m2 = __uint_as_float(__builtin_amdgcn_readlane(xu, 32));
        const float m3 = __uint_as_float(__builtin_amdgcn_readlane(xu, 48));
        float best;
        if (fl == 0x01010101u) {                 // common case: all strips rank-1
            best = fmaxf(fmaxf(u[0] + m0, u[1] + m1), fmaxf(u[2] + m2, u[3] + m3));
        } else {
            const unsigned au = __float_as_uint(a);
            const float* P = Pg + (size_t)c * 4096 + (size_t)j * 64;
            best = -3.0e38f;
            if (fl & 0x000000ffu) best = fmaxf(best, u[0] + m0);
            else {
#pragma unroll
                for (int r = 0; r < 16; ++r)
                    best = fmaxf(best, P[r] +
                        __uint_as_float(__builtin_amdgcn_readlane(au, r)));
            }
            if (fl & 0x0000ff00u) best = fmaxf(best, u[1] + m1);
            else {
#pragma unroll
                for (int r = 0; r < 16; ++r)
                    best = fmaxf(best, P[16 + r] +
                        __uint_as_float(__builtin_amdgcn_readlane(au, 16 + r)));
            }
            if (fl & 0x00ff0000u) best = fmaxf(best, u[2] + m2);
            else {
#pragma unroll
                for (int r = 0; r < 16; ++r)
                    best = fmaxf(best, P[32 + r] +
                        __uint_as_float(__builtin_amdgcn_readlane(au, 32 + r)));
            }
            if (fl & 0xff000000u) best = fmaxf(best, u[3] + m3);
            else {
#pragma unroll
                for (int r = 0; r < 16; ++r)
                    best = fmaxf(best, P[48 + r] +
                        __uint_as_float(__builtin_amdgcn_readlane(au, 48 + r)));
            }
        }
        const float mb = __uint_as_float(
            __builtin_amdgcn_readfirstlane(__float_as_uint(best)));
        base += (double)mb;
        a = best - mb;
        aB[(size_t)(c + 1) * 64 + j] = base + (double)a;
    }
}

// ---------------------------------------------------------------------------
// K4: phase 3 — per chunk, single wave, alphas in registers (readlane),
// backpointers + composed backtrack map. fp32, chunk-relative alphas.
// ---------------------------------------------------------------------------
__global__ __launch_bounds__(64) void k_phase3(
    const float* __restrict__ trans, const float* __restrict__ em,
    const double* __restrict__ aB, unsigned char* __restrict__ bp,
    unsigned char* __restrict__ gmap)
{
    __shared__ float sT[4096];            // 16 KB
    __shared__ unsigned char sbp[64 * 64];// 4 KB
    const int c = blockIdx.x;
    const int tid = threadIdx.x;          // = state j
    for (int x = tid; x < 4096; x += 64) sT[x] = trans[x];
    const double aref = aB[(size_t)c * 64];
    float a = (float)(aB[(size_t)c * 64 + tid] - aref);
    const int t0 = c * CHUNK;
    int nsteps = (T_LEN - 1) - t0; if (nsteps > CHUNK) nsteps = CHUNK;
    __syncthreads();

    for (int s = 0; s < nsteps; ++s) {
        const int t = t0 + 1 + s;
        const float e = em[(size_t)t * 64 + tid];
        float m = -3.0e38f; int bi = 0;
        const unsigned int au = __float_as_uint(a);
#pragma unroll
        for (int i = 0; i < 64; ++i) {
            const float ai = __uint_as_float(__builtin_amdgcn_readlane(au, i));
            const float v = sT[i * 64 + tid] + ai;
            if (v > m) { m = v; bi = i; }
        }
        a = e + m;
        sbp[s * 64 + tid] = (unsigned char)bi;
        bp[(size_t)t * 64 + tid] = (unsigned char)bi;
    }
    // composed map: tag at chunk end -> tag at chunk start
    int tag = tid;
    for (int r = nsteps - 1; r >= 0; --r) tag = sbp[r * 64 + tag];
    gmap[(size_t)c * 64 + tid] = (unsigned char)tag;
}

// ---------------------------------------------------------------------------
// K5: final scores + boundary tags via map composition.
// ---------------------------------------------------------------------------
__global__ __launch_bounds__(64) void k_final(
    const float* __restrict__ trans, const double* __restrict__ aB,
    const unsigned char* __restrict__ gmap, int* __restrict__ btag,
    float* __restrict__ out)
{
    __shared__ unsigned char sg[NCHUNK * 64];  // 16 KB
    __shared__ double sval[64];
    const int tid = threadIdx.x;
    for (int x = tid; x < NCHUNK * 64; x += 64) sg[x] = gmap[x];
    sval[tid] = aB[(size_t)NCHUNK * 64 + tid] + (double)trans[tid * 64 + EOS_ID];
    __syncthreads();
    if (tid == 0) {
        double bm = sval[0]; int bt = 0;
        for (int jj = 1; jj < 64; ++jj)
            if (sval[jj] > bm) { bm = sval[jj]; bt = jj; }
        out[0] = (float)bm;
        btag[NCHUNK] = bt;
        int cur = bt;
        for (int c = NCHUNK - 1; c >= 0; --c) {
            cur = sg[c * 64 + cur];
            btag[c] = cur;
        }
    }
}

// ---------------------------------------------------------------------------
// K6: per-chunk backtrack -> path written as float32.
// ---------------------------------------------------------------------------
__global__ __launch_bounds__(64) void k_path(
    const unsigned char* __restrict__ bp, const int* __restrict__ btag,
    float* __restrict__ out)
{
    __shared__ unsigned char sbp[64 * 64];
    const int c = blockIdx.x;
    const int tid = threadIdx.x;
    const int t0 = c * CHUNK;
    int nsteps = (T_LEN - 1) - t0; if (nsteps > CHUNK) nsteps = CHUNK;
    for (int r = 0; r < nsteps; ++r)
        sbp[r * 64 + tid] = bp[(size_t)(t0 + 1 + r) * 64 + tid];
    __syncthreads();
    if (tid == 0) {
        const int pe = t0 + nsteps;
        int cur = btag[c + 1];
        out[1 + pe] = (float)cur;
        for (int r = nsteps - 1; r >= 0; --r) {
            cur = sbp[r * 64 + cur];
            out[1 + t0 + r] = (float)cur;
        }
    }
}

// ---------------------------------------------------------------------------
extern "C" void kernel_launch(void* const* d_in, const int* in_sizes, int n_in,
                              void* d_out, int out_size, void* d_ws, size_t ws_size,
                              hipStream_t stream)
{
    const int*   feat = (const int*)d_in[0];
    const float* w    = (const float*)d_in[1];
    const float* tr   = (const float*)d_in[2];
    float* out = (float*)d_out;
    char*  ws  = (char*)d_ws;

    float*         em = (float*)(ws + EM_OFF);
    float*         Pg = (float*)(ws + P_OFF);
    double*        aB = (double*)(ws + AB_OFF);
    unsigned char* bp = (unsigned char*)(ws + BP_OFF);
    unsigned char* gm = (unsigned char*)(ws + G_OFF);
    int*           bt = (int*)(ws + BT_OFF);
    float*         U  = (float*)(ws + U_OFF);
    float*         V  = (float*)(ws + V_OFF);
    unsigned char* fl = (unsigned char*)(ws + FLG_OFF);

    k_emissions<<<T_LEN, 64, 0, stream>>>(feat, w, em);
    k_phase1   <<<NCHUNK * 4, 64, 0, stream>>>(tr, em, Pg, U, V, fl);
    k_phase2   <<<1,          64, 0, stream>>>(tr, em, Pg, U, V, fl, aB);
    k_phase3   <<<NCHUNK,     64, 0, stream>>>(tr, em, aB, bp, gm);
    k_final    <<<1,          64, 0, stream>>>(tr, aB, gm, bt, out);
    k_path     <<<NCHUNK,     64, 0, stream>>>(bp, bt, out);
}

// Round 8
// 450.910 us; speedup vs baseline: 1.1635x; 1.1635x over previous
//
#include <hip/hip_runtime.h>

#define T_LEN  16384
#define LTAG   64
#define F_PER  14
#define NCHUNK 256
#define CHUNK  64
#define BOS_ID 0
#define EOS_ID 1
#define NREG   10
#define REGSZ  500000      // 10 x 500000 = 5,000,000 = NB_FEATURES ; 2 MB per region
#define ALL1   0x01010101u

typedef __attribute__((ext_vector_type(4))) float f4;

// workspace layout (bytes)
static constexpr size_t EM_OFF  = 0;                                   // float[T*64]  4 MB
static constexpr size_t P_OFF   = EM_OFF + (size_t)T_LEN * 64 * 4;     // float[256*4096] 4 MB
static constexpr size_t AB_OFF  = P_OFF + (size_t)NCHUNK * 4096 * 4;   // double[257*64]
static constexpr size_t BP_OFF  = AB_OFF + (size_t)257 * 64 * 8;       // uchar[T*64] 1 MB
static constexpr size_t G_OFF   = BP_OFF + (size_t)T_LEN * 64;         // uchar[256*64]
static constexpr size_t BT_OFF  = G_OFF + (size_t)NCHUNK * 64;         // int[257]
static constexpr size_t U_OFF   = BT_OFF + 4096;                       // float[256*256]
static constexpr size_t V_OFF   = U_OFF + (size_t)NCHUNK * 256 * 4;    // float[256*64]
static constexpr size_t FLG_OFF = V_OFF + (size_t)NCHUNK * 64 * 4;     // uchar[256*4]
static constexpr size_t ZS_OFF  = FLG_OFF + 1024;                      // double[256*4]
static constexpr size_t WD_OFF  = ZS_OFF + 8192;                       // float[255*16]

// ---------------------------------------------------------------------------
// K1: emissions  em[t,l] = sum_f w[feat[t,l,f]]  (fp32)
// Region-sweep gather (r6 version, measured 114 us): idx in registers,
// table swept in 2 MB regions; long-lived 256-thread blocks keep co-resident
// waves in rough region lockstep so the active window stays hot in L2.
// ---------------------------------------------------------------------------
__global__ __launch_bounds__(256) void k_emissions(
    const int* __restrict__ idx, const float* __restrict__ w, float* __restrict__ em)
{
    const int tid = blockIdx.x * 256 + threadIdx.x;
    const int* p = idx + (size_t)tid * F_PER;
    int id[F_PER];
#pragma unroll
    for (int f = 0; f < F_PER; ++f) id[f] = __builtin_nontemporal_load(p + f);
    float s = 0.f;
    for (int r = 0; r < NREG; ++r) {
        const int lo = r * REGSZ;
        const int hi = lo + REGSZ;
#pragma unroll
        for (int f = 0; f < F_PER; ++f)
            if (id[f] >= lo && id[f] < hi) s += w[id[f]];
    }
    em[tid] = s;
}

// ---------------------------------------------------------------------------
// K2: phase 1 — per-chunk (max,+) transfer matrices, fp32, column-split,
// with max-plus rank-1 collapse early-exit. Collapsed strips emit (u,v,flag=1)
// instead of the full 16-column strip of Pg; non-collapsed emit Pg + flag=0.
// ---------------------------------------------------------------------------
__global__ __launch_bounds__(64) void k_phase1(
    const float* __restrict__ trans, const float* __restrict__ em, float* __restrict__ Pg,
    float* __restrict__ U, float* __restrict__ V, unsigned char* __restrict__ flags)
{
    __shared__ float sT[4096];      // 16 KB  sT[k*64+j] = T[k][j]
    __shared__ float sP[64 * 16];   // 4 KB   sP[j*16+i] = P[j][ib+i]
    __shared__ float sEm[64 * 64];  // 16 KB  emissions for this chunk
    __shared__ float su[64];
    __shared__ float sv[16];
    __shared__ float spart[256];
    const int bb  = blockIdx.x;
    const int c   = bb >> 2;
    const int st  = bb & 3;
    const int ib  = st << 4;
    const int tid = threadIdx.x;
    const int i0  = (tid & 3) << 2;
    const int j0  = (tid >> 2) << 2;
    const int t0  = c << 6;
    int nsteps = (T_LEN - 1) - t0; if (nsteps > CHUNK) nsteps = CHUNK;
    for (int x = tid; x < 4096; x += 64) sT[x] = trans[x];
    {   // stage emissions em[t0+1 .. t0+nsteps][:] -> sEm[s*64+j]
        const float* eg = em + (size_t)(t0 + 1) * 64;
        for (int x = tid * 4; x < nsteps * 64; x += 256)
            *(f4*)(sEm + x) = *(const f4*)(eg + x);
    }
    __syncthreads();

    float acc[4][4];
    // init step s=0: P[j][i] = e0[j] + T[ib+i][j]
    {
        const f4 e = *(const f4*)(sEm + j0);
#pragma unroll
        for (int jj = 0; jj < 4; ++jj) {
#pragma unroll
            for (int ii = 0; ii < 4; ++ii)
                acc[jj][ii] = e[jj] + sT[(ib + i0 + ii) * 64 + (j0 + jj)];
            f4 row = { acc[jj][0], acc[jj][1], acc[jj][2], acc[jj][3] };
            *(f4*)(sP + (j0 + jj) * 16 + i0) = row;
        }
    }
    __syncthreads();

    int coll = -1;
    for (int s = 1; s < nsteps; ++s) {
        const f4 e = *(const f4*)(sEm + s * 64 + j0);
#pragma unroll
        for (int jj = 0; jj < 4; ++jj)
#pragma unroll
            for (int ii = 0; ii < 4; ++ii) acc[jj][ii] = -3.0e38f;
#pragma unroll 8
        for (int k = 0; k < 64; k += 2) {
            const f4 ta = *(const f4*)(sT + k * 64 + j0);
            const f4 tb = *(const f4*)(sT + (k + 1) * 64 + j0);
            const f4 pa = *(const f4*)(sP + k * 16 + i0);
            const f4 pb = *(const f4*)(sP + (k + 1) * 16 + i0);
#pragma unroll
            for (int jj = 0; jj < 4; ++jj)
#pragma unroll
                for (int ii = 0; ii < 4; ++ii)
                    acc[jj][ii] = fmaxf(fmaxf(acc[jj][ii], ta[jj] + pa[ii]),
                                        tb[jj] + pb[ii]);
        }
        __syncthreads();
#pragma unroll
        for (int jj = 0; jj < 4; ++jj) {
            f4 row = { acc[jj][0] + e[jj], acc[jj][1] + e[jj],
                       acc[jj][2] + e[jj], acc[jj][3] + e[jj] };
            *(f4*)(sP + (j0 + jj) * 16 + i0) = row;
        }
        __syncthreads();
        // rank-1 check: (P[j][i]-P[j][0]) must equal (P[0][i]-P[0][0]) for all i,j
        {
            const f4 refi = *(const f4*)(sP + i0);   // row j=0, this thread's cols
            const float ref0 = sP[0];
            float dev = 0.f;
#pragma unroll
            for (int jj = 0; jj < 4; ++jj) {
                const float cj = sP[(j0 + jj) * 16];
#pragma unroll
                for (int ii = 0; ii < 4; ++ii) {
                    const float val = acc[jj][ii] + e[jj];
                    dev = fmaxf(dev, fabsf((val - cj) - (refi[ii] - ref0)));
                }
            }
            if (__ballot(dev <= 1.0e-2f) == ~0ULL) { coll = s; break; }
        }
    }

    if (coll >= 0) {
        // P = u + v ; run cheap vector recursion on u for remaining steps
        if (tid < 16) sv[tid] = sP[tid] - sP[0];
        su[tid] = sP[tid * 16];
        __syncthreads();
        const int kq = tid & 3;            // k-group (16 k's)
        const int jq = (tid >> 2) << 2;    // 4 j's
        for (int s = coll + 1; s < nsteps; ++s) {
            float pm0 = -3.0e38f, pm1 = -3.0e38f, pm2 = -3.0e38f, pm3 = -3.0e38f;
#pragma unroll
            for (int kk = 0; kk < 16; ++kk) {
                const int k = (kq << 4) + kk;
                const float uk = su[k];
                const f4 ta = *(const f4*)(sT + k * 64 + jq);
                pm0 = fmaxf(pm0, ta[0] + uk);
                pm1 = fmaxf(pm1, ta[1] + uk);
                pm2 = fmaxf(pm2, ta[2] + uk);
                pm3 = fmaxf(pm3, ta[3] + uk);
            }
            spart[(jq + 0) * 4 + kq] = pm0;
            spart[(jq + 1) * 4 + kq] = pm1;
            spart[(jq + 2) * 4 + kq] = pm2;
            spart[(jq + 3) * 4 + kq] = pm3;
            __syncthreads();                       // spart visible; su reads done
            const f4 pr = *(const f4*)(spart + tid * 4);
            const float un = sEm[s * 64 + tid] +
                fmaxf(fmaxf(pr[0], pr[1]), fmaxf(pr[2], pr[3]));
            su[tid] = un;
            __syncthreads();                       // su visible; spart reads done
        }
        // rank-1 emit: u (64), v (16), flag=1 — no Pg write
        U[(size_t)c * 256 + tid * 4 + st] = su[tid];
        if (tid < 16) V[(size_t)c * 64 + ib + tid] = sv[tid];
        if (tid == 0) flags[c * 4 + st] = 1;
        return;
    }

    // matrix-mode writeout + flag=0
#pragma unroll
    for (int jj = 0; jj < 4; ++jj) {
        const f4 row = *(const f4*)(sP + (j0 + jj) * 16 + i0);
        *(f4*)(Pg + (size_t)c * 4096 + (j0 + jj) * 64 + ib + i0) = row;
    }
    if (tid == 0) flags[c * 4 + st] = 0;
}

// ---------------------------------------------------------------------------
// K2b: boundary compose — W_c[t][s] = max_{i in strip t}(v_{c+1}[i]+u_{c,s}[i])
// Valid (and used) only when chunks c and c+1 are both fully rank-1.
// ---------------------------------------------------------------------------
__global__ __launch_bounds__(64) void k_phase1b(
    const float* __restrict__ U, const float* __restrict__ V,
    const unsigned char* __restrict__ flags, float* __restrict__ Wd)
{
    const int c = blockIdx.x;              // 0..254
    const int lane = threadIdx.x;
    const unsigned* fl4 = (const unsigned*)flags;
    if (fl4[c] != ALL1 || fl4[c + 1] != ALL1) return;
    if (lane >= 16) return;
    const int t = lane >> 2, s = lane & 3;
    const float* u = U + (size_t)c * 256 + s;
    const float* v = V + (size_t)(c + 1) * 64 + t * 16;
    float m = -3.0e38f;
#pragma unroll
    for (int k = 0; k < 16; ++k)
        m = fmaxf(m, v[k] + u[(t * 16 + k) * 4]);
    Wd[(size_t)c * 16 + lane] = m;
}

// ---------------------------------------------------------------------------
// K3: the only serial kernel — scan over 4-vectors z_c with 4x4 max-plus
// matrices W_c (16 fp64 add+max per chunk, wave-uniform, no shuffles in the
// hot path). Dense chunks fall back to a readlane alpha apply. Stores z_c
// for every rank-1 chunk; stores aB rows only on the dense path.
// ---------------------------------------------------------------------------
__global__ __launch_bounds__(64) void k_scan(
    const float* __restrict__ trans, const float* __restrict__ em,
    const float* __restrict__ Pg, const float* __restrict__ U,
    const float* __restrict__ V, const unsigned char* __restrict__ flags,
    const float* __restrict__ Wd, double* __restrict__ zs, double* __restrict__ aB)
{
    const int j = threadIdx.x;
    double a = (double)trans[BOS_ID * 64 + j] + (double)em[j];
    aB[j] = a;
    const unsigned* fl4 = (const unsigned*)flags;
    int c = 0;
    while (c < NCHUNK) {
        if (fl4[c] != ALL1) {
            // dense chunk c: a <- max_i(P[j][i] + a[i])
            const float* P = Pg + (size_t)c * 4096 + (size_t)j * 64;
            double an = -1.0e300;
            for (int i = 0; i < 64; ++i)
                an = fmax(an, (double)P[i] + __shfl(a, i));
            a = an;
            aB[(size_t)(c + 1) * 64 + j] = a;
            ++c;
            continue;
        }
        // enter z-mode: z_c[s] = max_{i in s}(v_c[i] + a[i])
        double x = (double)V[(size_t)c * 64 + j] + a;
        x = fmax(x, __shfl_xor(x, 1));
        x = fmax(x, __shfl_xor(x, 2));
        x = fmax(x, __shfl_xor(x, 4));
        x = fmax(x, __shfl_xor(x, 8));
        double z0 = __shfl(x, 0),  z1 = __shfl(x, 16);
        double z2 = __shfl(x, 32), z3 = __shfl(x, 48);
        {
            double zz = (j == 1) ? z1 : (j == 2) ? z2 : (j == 3) ? z3 : z0;
            if (j < 4) zs[c * 4 + j] = zz;
        }
        // z-mode sweep
        while (c + 1 < NCHUNK && fl4[c + 1] == ALL1) {
            const float* Wc = Wd + (size_t)c * 16;
            const double n0 = fmax(fmax(z0 + (double)Wc[0],  z1 + (double)Wc[1]),
                                   fmax(z2 + (double)Wc[2],  z3 + (double)Wc[3]));
            const double n1 = fmax(fmax(z0 + (double)Wc[4],  z1 + (double)Wc[5]),
                                   fmax(z2 + (double)Wc[6],  z3 + (double)Wc[7]));
            const double n2 = fmax(fmax(z0 + (double)Wc[8],  z1 + (double)Wc[9]),
                                   fmax(z2 + (double)Wc[10], z3 + (double)Wc[11]));
            const double n3 = fmax(fmax(z0 + (double)Wc[12], z1 + (double)Wc[13]),
                                   fmax(z2 + (double)Wc[14], z3 + (double)Wc[15]));
            z0 = n0; z1 = n1; z2 = n2; z3 = n3;
            ++c;
            double zz = (j == 1) ? z1 : (j == 2) ? z2 : (j == 3) ? z3 : z0;
            if (j < 4) zs[c * 4 + j] = zz;
        }
        if (c + 1 >= NCHUNK) return;    // z_255 stored; k_phase2b writes aB[256]
        // next chunk dense: materialize alpha entering c+1 (k_phase2b also
        // writes aB[c+1] from the same z — identical value)
        const f4 u = *(const f4*)(U + (size_t)c * 256 + j * 4);
        a = fmax(fmax(z0 + (double)u[0], z1 + (double)u[1]),
                 fmax(z2 + (double)u[2], z3 + (double)u[3]));
        ++c;
    }
}

// ---------------------------------------------------------------------------
// K3b: parallel boundary-alpha reconstruction: aB[c+1][j] = max_s(u_c,s[j]+z_c[s])
// ---------------------------------------------------------------------------
__global__ __launch_bounds__(64) void k_phase2b(
    const float* __restrict__ U, const unsigned char* __restrict__ flags,
    const double* __restrict__ zs, double* __restrict__ aB)
{
    const int c = blockIdx.x;              // 0..255, writes aB[c+1]
    const int j = threadIdx.x;
    const unsigned* fl4 = (const unsigned*)flags;
    if (fl4[c] != ALL1) return;            // dense: k_scan wrote aB[c+1]
    const f4 u = *(const f4*)(U + (size_t)c * 256 + j * 4);
    const double z0 = zs[c * 4 + 0], z1 = zs[c * 4 + 1];
    const double z2 = zs[c * 4 + 2], z3 = zs[c * 4 + 3];
    aB[(size_t)(c + 1) * 64 + j] =
        fmax(fmax(z0 + (double)u[0], z1 + (double)u[1]),
             fmax(z2 + (double)u[2], z3 + (double)u[3]));
}

// ---------------------------------------------------------------------------
// K4: phase 3 — per chunk, single wave, alphas in registers (readlane),
// backpointers + composed backtrack map. fp32, chunk-relative alphas.
// ---------------------------------------------------------------------------
__global__ __launch_bounds__(64) void k_phase3(
    const float* __restrict__ trans, const float* __restrict__ em,
    const double* __restrict__ aB, unsigned char* __restrict__ bp,
    unsigned char* __restrict__ gmap)
{
    __shared__ float sT[4096];            // 16 KB
    __shared__ unsigned char sbp[64 * 64];// 4 KB
    const int c = blockIdx.x;
    const int tid = threadIdx.x;          // = state j
    for (int x = tid; x < 4096; x += 64) sT[x] = trans[x];
    const double aref = aB[(size_t)c * 64];
    float a = (float)(aB[(size_t)c * 64 + tid] - aref);
    const int t0 = c * CHUNK;
    int nsteps = (T_LEN - 1) - t0; if (nsteps > CHUNK) nsteps = CHUNK;
    __syncthreads();

    for (int s = 0; s < nsteps; ++s) {
        const int t = t0 + 1 + s;
        const float e = em[(size_t)t * 64 + tid];
        float m = -3.0e38f; int bi = 0;
        const unsigned int au = __float_as_uint(a);
#pragma unroll
        for (int i = 0; i < 64; ++i) {
            const float ai = __uint_as_float(__builtin_amdgcn_readlane(au, i));
            const float v = sT[i * 64 + tid] + ai;
            if (v > m) { m = v; bi = i; }
        }
        a = e + m;
        sbp[s * 64 + tid] = (unsigned char)bi;
        bp[(size_t)t * 64 + tid] = (unsigned char)bi;
    }
    // composed map: tag at chunk end -> tag at chunk start
    int tag = tid;
    for (int r = nsteps - 1; r >= 0; --r) tag = sbp[r * 64 + tag];
    gmap[(size_t)c * 64 + tid] = (unsigned char)tag;
}

// ---------------------------------------------------------------------------
// K5: final scores + boundary tags via map composition.
// ---------------------------------------------------------------------------
__global__ __launch_bounds__(64) void k_final(
    const float* __restrict__ trans, const double* __restrict__ aB,
    const unsigned char* __restrict__ gmap, int* __restrict__ btag,
    float* __restrict__ out)
{
    __shared__ unsigned char sg[NCHUNK * 64];  // 16 KB
    __shared__ double sval[64];
    const int tid = threadIdx.x;
    for (int x = tid; x < NCHUNK * 64; x += 64) sg[x] = gmap[x];
    sval[tid] = aB[(size_t)NCHUNK * 64 + tid] + (double)trans[tid * 64 + EOS_ID];
    __syncthreads();
    if (tid == 0) {
        double bm = sval[0]; int bt = 0;
        for (int jj = 1; jj < 64; ++jj)
            if (sval[jj] > bm) { bm = sval[jj]; bt = jj; }
        out[0] = (float)bm;
        btag[NCHUNK] = bt;
        int cur = bt;
        for (int c = NCHUNK - 1; c >= 0; --c) {
            cur = sg[c * 64 + cur];
            btag[c] = cur;
        }
    }
}

// ---------------------------------------------------------------------------
// K6: per-chunk backtrack -> path written as float32.
// ---------------------------------------------------------------------------
__global__ __launch_bounds__(64) void k_path(
    const unsigned char* __restrict__ bp, const int* __restrict__ btag,
    float* __restrict__ out)
{
    __shared__ unsigned char sbp[64 * 64];
    const int c = blockIdx.x;
    const int tid = threadIdx.x;
    const int t0 = c * CHUNK;
    int nsteps = (T_LEN - 1) - t0; if (nsteps > CHUNK) nsteps = CHUNK;
    for (int r = 0; r < nsteps; ++r)
        sbp[r * 64 + tid] = bp[(size_t)(t0 + 1 + r) * 64 + tid];
    __syncthreads();
    if (tid == 0) {
        const int pe = t0 + nsteps;
        int cur = btag[c + 1];
        out[1 + pe] = (float)cur;
        for (int r = nsteps - 1; r >= 0; --r) {
            cur = sbp[r * 64 + cur];
            out[1 + t0 + r] = (float)cur;
        }
    }
}

// ---------------------------------------------------------------------------
extern "C" void kernel_launch(void* const* d_in, const int* in_sizes, int n_in,
                              void* d_out, int out_size, void* d_ws, size_t ws_size,
                              hipStream_t stream)
{
    const int*   feat = (const int*)d_in[0];
    const float* w    = (const float*)d_in[1];
    const float* tr   = (const float*)d_in[2];
    float* out = (float*)d_out;
    char*  ws  = (char*)d_ws;

    float*         em = (float*)(ws + EM_OFF);
    float*         Pg = (float*)(ws + P_OFF);
    double*        aB = (double*)(ws + AB_OFF);
    unsigned char* bp = (unsigned char*)(ws + BP_OFF);
    unsigned char* gm = (unsigned char*)(ws + G_OFF);
    int*           bt = (int*)(ws + BT_OFF);
    float*         U  = (float*)(ws + U_OFF);
    float*         V  = (float*)(ws + V_OFF);
    unsigned char* fl = (unsigned char*)(ws + FLG_OFF);
    double*        zs = (double*)(ws + ZS_OFF);
    float*         Wd = (float*)(ws + WD_OFF);

    k_emissions<<<(T_LEN * LTAG) / 256, 256, 0, stream>>>(feat, w, em);
    k_phase1   <<<NCHUNK * 4, 64, 0, stream>>>(tr, em, Pg, U, V, fl);
    k_phase1b  <<<NCHUNK - 1, 64, 0, stream>>>(U, V, fl, Wd);
    k_scan     <<<1,          64, 0, stream>>>(tr, em, Pg, U, V, fl, Wd, zs, aB);
    k_phase2b  <<<NCHUNK,     64, 0, stream>>>(U, fl, zs, aB);
    k_phase3   <<<NCHUNK,     64, 0, stream>>>(tr, em, aB, bp, gm);
    k_final    <<<1,          64, 0, stream>>>(tr, aB, gm, bt, out);
    k_path     <<<NCHUNK,     64, 0, stream>>>(bp, bt, out);
}

// Round 9
// 291.229 us; speedup vs baseline: 1.8015x; 1.5483x over previous
//
#include <hip/hip_runtime.h>

#define T_LEN  16384
#define LTAG   64
#define F_PER  14
#define NCHUNK 256
#define CHUNK  64
#define BOS_ID 0
#define EOS_ID 1
#define NREG   10
#define REGSZ  500000
#define WARM   48

typedef __attribute__((ext_vector_type(4))) float f4;
typedef __attribute__((ext_vector_type(4))) int   i4;

static constexpr size_t EM_OFF = 0;
static constexpr size_t AB_OFF = EM_OFF + (size_t)T_LEN * 64 * 4;
static constexpr size_t BP_OFF = AB_OFF + (size_t)257 * 64 * 4;
static constexpr size_t G_OFF  = BP_OFF + (size_t)T_LEN * 64;
static constexpr size_t BT_OFF = G_OFF + (size_t)NCHUNK * 64;
static constexpr size_t PS_OFF = BT_OFF + 4096;

__global__ __launch_bounds__(256) void k_emissions(
    const int* __restrict__ idx, const float* __restrict__ w, float* __restrict__ em)
{
    __shared__ int sIdx[256 * F_PER];
    const int tid = threadIdx.x;
    const int* g = idx + (size_t)blockIdx.x * (256 * F_PER);
    for (int x = tid * 4; x < 256 * F_PER; x += 1024)
        *(i4*)(sIdx + x) = __builtin_nontemporal_load((const i4*)(g + x));
    __syncthreads();
    int id[F_PER];
#pragma unroll
    for (int f = 0; f < F_PER; ++f) id[f] = sIdx[tid * F_PER + f];
    float s = 0.f;
    for (int r = 0; r < NREG; ++r) {
        const int lo = r * REGSZ;
        const int hi = lo + REGSZ;
#pragma unroll
        for (int f = 0; f < F_PER; ++f)
            if (id[f] >= lo && id[f] < hi) s += w[id[f]];
    }
    em[(size_t)blockIdx.x * 256 + tid] = s;
}

__global__ __launch_bounds__(64) void k_warm(
    const float* __restrict__ trans, const float* __restrict__ em,
    float* __restrict__ aB)
{
    __shared__ float sT[4096];
    const int c = blockIdx.x;                  // 0..256
    const int j = threadIdx.x;
    for (int x = j; x < 4096; x += 64) sT[x] = trans[x];
    __syncthreads();
    float a;
    if (c == 0) {
        a = trans[BOS_ID * 64 + j] + em[j];
    } else {
        const int tEnd = (c < NCHUNK) ? c * CHUNK : (T_LEN - 1);
        const int tw = tEnd - WARM;
        a = em[(size_t)tw * 64 + j];
        for (int t = tw + 1; t <= tEnd; ++t) {
            const float e = em[(size_t)t * 64 + j];
            float m = -3.0e38f;
            const unsigned au = __float_as_uint(a);
#pragma unroll
            for (int i = 0; i < 64; ++i) {
                const float ai = __uint_as_float(__builtin_amdgcn_readlane(au, i));
                m = fmaxf(m, sT[i * 64 + j] + ai);
            }
            a = e + m;
        }
    }
    aB[(size_t)c * 64 + j] = a;
}

__global__ __launch_bounds__(64) void k_phase3(
    const float* __restrict__ trans, const float* __restrict__ em,
    const float* __restrict__ aB, unsigned char* __restrict__ bp,
    unsigned char* __restrict__ gmap)
{
    __shared__ float sT[4096];
    __shared__ unsigned char sbp[64 * 64];
    const int c = blockIdx.x;
    const int tid = threadIdx.x;
    for (int x = tid; x < 4096; x += 64) sT[x] = trans[x];
    float a = aB[(size_t)c * 64 + tid];
    const int t0 = c * CHUNK;
    int nsteps = (T_LEN - 1) - t0; if (nsteps > CHUNK) nsteps = CHUNK;
    __syncthreads();

    for (int s = 0; s < nsteps; ++s) {
        const int t = t0 + 1 + s;
        const float e = em[(size_t)t * 64 + tid];
        float m = -3.0e38f; int bi = 0;
        const unsigned int au = __float_as_uint(a);
#pragma unroll
        for (int i = 0; i < 64; ++i) {
            const float ai = __uint_as_float(__builtin_amdgcn_readlane(au, i));
            const float v = sT[i * 64 + tid] + ai;
            if (v > m) { m = v; bi = i; }
        }
        a = e + m;
        sbp[s * 64 + tid] = (unsigned char)bi;
        bp[(size_t)t * 64 + tid] = (unsigned char)bi;
    }
    int tag = tid;
    for (int r = nsteps - 1; r >= 0; --r) tag = sbp[r * 64 + tag];
    gmap[(size_t)c * 64 + tid] = (unsigned char)tag;
}

__global__ __launch_bounds__(64) void k_final(
    const float* __restrict__ trans, const float* __restrict__ aB,
    const unsigned char* __restrict__ gmap, int* __restrict__ btag)
{
    __shared__ unsigned char sg[NCHUNK * 64];
    __shared__ float sval[64];
    const int tid = threadIdx.x;
    for (int x = tid; x < NCHUNK * 64; x += 64) sg[x] = gmap[x];
    sval[tid] = aB[(size_t)NCHUNK * 64 + tid] + trans[tid * 64 + EOS_ID];
    __syncthreads();
    if (tid == 0) {
        float bm = sval[0]; int bt = 0;
        for (int jj = 1; jj < 64; ++jj)
            if (sval[jj] > bm) { bm = sval[jj]; bt = jj; }
        btag[NCHUNK] = bt;
        int cur = bt;
        for (int c = NCHUNK - 1; c >= 0; --c) {
            cur = sg[c * 64 + cur];
            btag[c] = cur;
        }
    }
}

__global__ __launch_bounds__(64) void k_path(
    const unsigned char* __restrict__ bp, const int* __restrict__ btag,
    float* __restrict__ out)
{
    __shared__ unsigned char sbp[64 * 64];
    const int c = blockIdx.x;
    const int tid = threadIdx.x;
    const int t0 = c * CHUNK;
    int nsteps = (T_LEN - 1) - t0; if (nsteps > CHUNK) nsteps = CHUNK;
    for (int r = 0; r < nsteps; ++r)
        sbp[r * 64 + tid] = bp[(size_t)(t0 + 1 + r) * 64 + tid];
    __syncthreads();
    if (tid == 0) {
        const int pe = t0 + nsteps;
        int cur = btag[c + 1];
        out[1 + pe] = (float)cur;
        for (int r = nsteps - 1; r >= 0; --r) {
            cur = sbp[r * 64 + cur];
            out[1 + t0 + r] = (float)cur;
        }
    }
}

__global__ __launch_bounds__(64) void k_score(
    const float* __restrict__ trans, const float* __restrict__ em,
    const float* __restrict__ out, double* __restrict__ partial)
{
    const int c = blockIdx.x;
    const int s = threadIdx.x;
    const int t = c * 64 + s;
    const int pt = (int)out[1 + t];
    double term;
    if (t == 0) {
        term = (double)trans[BOS_ID * 64 + pt] + (double)em[pt];
    } else {
        const int pp = (int)out[t];
        term = (double)trans[pp * 64 + pt] + (double)em[(size_t)t * 64 + pt];
    }
    if (t == T_LEN - 1) term += (double)trans[pt * 64 + EOS_ID];
#pragma unroll
    for (int o = 1; o < 64; o <<= 1) term += __shfl_xor(term, o);
    if (s == 0) partial[c] = term;
}

__global__ __launch_bounds__(64) void k_sfin(
    const double* __restrict__ partial, float* __restrict__ out)
{
    const int tid = threadIdx.x;
    double s = partial[tid] + partial[64 + tid] + partial[128 + tid] + partial[192 + tid];
#pragma unroll
    for (int o = 1; o < 64; o <<= 1) s += __shfl_xor(s, o);
    if (tid == 0) out[0] = (float)s;
}

extern "C" void kernel_launch(void* const* d_in, const int* in_sizes, int n_in,
                              void* d_out, int out_size, void* d_ws, size_t ws_size,
                              hipStream_t stream)
{
    const int*   feat = (const int*)d_in[0];
    const float* w    = (const float*)d_in[1];
    const float* tr   = (const float*)d_in[2];
    float* out = (float*)d_out;
    char*  ws  = (char*)d_ws;

    float*         em = (float*)(ws + EM_OFF);
    float*         aB = (float*)(ws + AB_OFF);
    unsigned char* bp = (unsigned char*)(ws + BP_OFF);
    unsigned char* gm = (unsigned char*)(ws + G_OFF);
    int*           bt = (int*)(ws + BT_OFF);
    double*        ps = (double*)(ws + PS_OFF);

    k_emissions<<<(T_LEN * LTAG) / 256, 256, 0, stream>>>(feat, w, em);
    k_warm     <<<NCHUNK + 1, 64, 0, stream>>>(tr, em, aB);
    k_phase3   <<<NCHUNK,     64, 0, stream>>>(tr, em, aB, bp, gm);
    k_final    <<<1,          64, 0, stream>>>(tr, aB, gm, bt);
    k_path     <<<NCHUNK,     64, 0, stream>>>(bp, bt, out);
    k_score    <<<NCHUNK,     64, 0, stream>>>(tr, em, out, ps);
    k_sfin     <<<1,          64, 0, stream>>>(ps, out);
}

// Round 10
// 279.355 us; speedup vs baseline: 1.8781x; 1.0425x over previous
//
#include <hip/hip_runtime.h>

#define T_LEN  16384
#define LTAG   64
#define F_PER  14
#define NCHUNK 256
#define CHUNK  64
#define BOS_ID 0
#define EOS_ID 1
#define NREG   10
#define REGSZ  500000      // 10 x 500000 = 5,000,000 = NB_FEATURES ; 2 MB/region
#define WARM   48          // warm-up steps before each chunk (coalescence ~10-30)

typedef __attribute__((ext_vector_type(4))) int i4;

// workspace layout (bytes)
static constexpr size_t EM_OFF = 0;                                 // float[T*64] 4 MB
static constexpr size_t BP_OFF = EM_OFF + (size_t)T_LEN * 64 * 4;   // uchar[T*64] 1 MB
static constexpr size_t G_OFF  = BP_OFF + (size_t)T_LEN * 64;       // uchar[256*64]
static constexpr size_t BT_OFF = G_OFF + (size_t)NCHUNK * 64;       // int[257]
static constexpr size_t AE_OFF = BT_OFF + 2048;                     // float[64] final alpha
static constexpr size_t PS_OFF = AE_OFF + 512;                      // double[256]

// ---------------------------------------------------------------------------
// K1: emissions  em[t,l] = sum_f w[feat[t,l,f]]  (fp32)
// Region-sweep gather + COALESCED LDS idx staging + PER-F ACCUMULATORS:
// the old single accumulator serialized ~140 predicated loads through one
// fp32 add chain (each L2 gather's latency exposed). 14 independent chains
// (one per f) let the loads pipeline; summed pairwise at the end.
// ---------------------------------------------------------------------------
__global__ __launch_bounds__(256) void k_emissions(
    const int* __restrict__ idx, const float* __restrict__ w, float* __restrict__ em)
{
    __shared__ int sIdx[256 * F_PER];          // 14 KB
    const int tid = threadIdx.x;
    const int* g = idx + (size_t)blockIdx.x * (256 * F_PER);
    for (int x = tid * 4; x < 256 * F_PER; x += 1024)
        *(i4*)(sIdx + x) = __builtin_nontemporal_load((const i4*)(g + x));
    __syncthreads();
    int id[F_PER];
#pragma unroll
    for (int f = 0; f < F_PER; ++f) id[f] = sIdx[tid * F_PER + f];
    float sf[F_PER];
#pragma unroll
    for (int f = 0; f < F_PER; ++f) sf[f] = 0.f;
    for (int r = 0; r < NREG; ++r) {
        const int lo = r * REGSZ;
        const int hi = lo + REGSZ;
#pragma unroll
        for (int f = 0; f < F_PER; ++f)
            if (id[f] >= lo && id[f] < hi) sf[f] += w[id[f]];
    }
    // pairwise sum of the 14 partials
    float s = 0.f;
#pragma unroll
    for (int f = 0; f < F_PER; f += 2) s += sf[f] + sf[f + 1];
    em[(size_t)blockIdx.x * 256 + tid] = s;
}

// ---------------------------------------------------------------------------
// K2: phase 3 with self-warm (replaces k_warm + k_phase3).
// Each chunk runs WARM neutral-init steps to reach its boundary alpha
// (coalescence makes the result exact up to an additive constant, which
// cancels in every argmax), then the 64 real steps emitting backpointers
// and the composed backtrack map. Chunk 255 exports the final alpha.
// ---------------------------------------------------------------------------
__global__ __launch_bounds__(64) void k_phase3(
    const float* __restrict__ trans, const float* __restrict__ em,
    unsigned char* __restrict__ bp, unsigned char* __restrict__ gmap,
    float* __restrict__ aEnd)
{
    __shared__ float sT[4096];            // 16 KB  sT[i*64+j] = T[i][j]
    __shared__ unsigned char sbp[64 * 64];// 4 KB
    const int c = blockIdx.x;
    const int tid = threadIdx.x;          // = state j
    for (int x = tid; x < 4096; x += 64) sT[x] = trans[x];
    const int t0 = c * CHUNK;
    int nsteps = (T_LEN - 1) - t0; if (nsteps > CHUNK) nsteps = CHUNK;
    __syncthreads();

    float a;
    if (c == 0) {
        a = sT[BOS_ID * 64 + tid] + em[tid];      // exact initial alpha
    } else {
        const int tw = t0 - WARM;
        a = em[(size_t)tw * 64 + tid];            // neutral init
        for (int t = tw + 1; t <= t0; ++t) {
            const float e = em[(size_t)t * 64 + tid];
            float m = -3.0e38f;
            const unsigned au = __float_as_uint(a);
#pragma unroll
            for (int i = 0; i < 64; ++i) {
                const float ai = __uint_as_float(__builtin_amdgcn_readlane(au, i));
                m = fmaxf(m, sT[i * 64 + tid] + ai);
            }
            a = e + m;
        }
    }

    for (int s = 0; s < nsteps; ++s) {
        const int t = t0 + 1 + s;
        const float e = em[(size_t)t * 64 + tid];
        float m = -3.0e38f; int bi = 0;
        const unsigned au = __float_as_uint(a);
#pragma unroll
        for (int i = 0; i < 64; ++i) {
            const float ai = __uint_as_float(__builtin_amdgcn_readlane(au, i));
            const float v = sT[i * 64 + tid] + ai;
            if (v > m) { m = v; bi = i; }          // strict > keeps first max
        }
        a = e + m;
        sbp[s * 64 + tid] = (unsigned char)bi;
        bp[(size_t)t * 64 + tid] = (unsigned char)bi;
    }
    if (c == NCHUNK - 1) aEnd[tid] = a;            // alpha at t = 16383
    // composed map: tag at chunk end -> tag at chunk start
    int tag = tid;
    for (int r = nsteps - 1; r >= 0; --r) tag = sbp[r * 64 + tag];
    gmap[(size_t)c * 64 + tid] = (unsigned char)tag;
}

// ---------------------------------------------------------------------------
// K3: final tag (argmax of final alpha + EOS column — additive constant
// cancels) + boundary tags via backtrack-map composition.
// ---------------------------------------------------------------------------
__global__ __launch_bounds__(64) void k_final(
    const float* __restrict__ trans, const float* __restrict__ aEnd,
    const unsigned char* __restrict__ gmap, int* __restrict__ btag)
{
    __shared__ unsigned char sg[NCHUNK * 64];  // 16 KB
    __shared__ float sval[64];
    const int tid = threadIdx.x;
    for (int x = tid; x < NCHUNK * 64; x += 64) sg[x] = gmap[x];
    sval[tid] = aEnd[tid] + trans[tid * 64 + EOS_ID];
    __syncthreads();
    if (tid == 0) {
        float bm = sval[0]; int bt = 0;
        for (int jj = 1; jj < 64; ++jj)
            if (sval[jj] > bm) { bm = sval[jj]; bt = jj; }
        btag[NCHUNK] = bt;                 // = path[16383]
        int cur = bt;
        for (int c = NCHUNK - 1; c >= 0; --c) {
            cur = sg[c * 64 + cur];
            btag[c] = cur;                 // = path[c*64]
        }
    }
}

// ---------------------------------------------------------------------------
// K4: per-chunk backtrack -> path floats + EXACT fp64 score terms for this
// chunk's covered range t in (t0, t0+nsteps] (plus t=0 / EOS specials).
// ---------------------------------------------------------------------------
__global__ __launch_bounds__(64) void k_path_score(
    const float* __restrict__ trans, const float* __restrict__ em,
    const unsigned char* __restrict__ bp, const int* __restrict__ btag,
    float* __restrict__ out, double* __restrict__ partial)
{
    __shared__ unsigned char sbp[64 * 64];
    __shared__ unsigned char sTag[CHUNK + 1];
    const int c = blockIdx.x;
    const int tid = threadIdx.x;
    const int t0 = c * CHUNK;
    int nsteps = (T_LEN - 1) - t0; if (nsteps > CHUNK) nsteps = CHUNK;
    for (int r = 0; r < nsteps; ++r)
        sbp[r * 64 + tid] = bp[(size_t)(t0 + 1 + r) * 64 + tid];
    __syncthreads();
    if (tid == 0) {
        int cur = btag[c + 1];
        sTag[nsteps] = (unsigned char)cur;
        for (int r = nsteps - 1; r >= 0; --r) {
            cur = sbp[r * 64 + cur];
            sTag[r] = (unsigned char)cur;
        }
    }
    __syncthreads();
    // path writes (parallel, coalesced)
    if (tid < nsteps) out[1 + t0 + tid] = (float)sTag[tid];
    if (c == NCHUNK - 1 && tid == 0) out[1 + (T_LEN - 1)] = (float)sTag[nsteps];
    // score terms
    double term = 0.0;
    if (tid < nsteps) {
        const int t = t0 + 1 + tid;
        const int pt = sTag[tid + 1], pp = sTag[tid];
        term = (double)trans[pp * 64 + pt] + (double)em[(size_t)t * 64 + pt];
    }
    if (c == 0 && tid == 0) {
        const int p0 = sTag[0];
        term += (double)trans[BOS_ID * 64 + p0] + (double)em[p0];
    }
    if (c == NCHUNK - 1 && tid == 0)
        term += (double)trans[(int)sTag[nsteps] * 64 + EOS_ID];
#pragma unroll
    for (int o = 1; o < 64; o <<= 1) term += __shfl_xor(term, o);
    if (tid == 0) partial[c] = term;
}

// ---------------------------------------------------------------------------
// K5: reduce 256 partials -> out[0]
// ---------------------------------------------------------------------------
__global__ __launch_bounds__(64) void k_sfin(
    const double* __restrict__ partial, float* __restrict__ out)
{
    const int tid = threadIdx.x;
    double s = partial[tid] + partial[64 + tid] + partial[128 + tid] + partial[192 + tid];
#pragma unroll
    for (int o = 1; o < 64; o <<= 1) s += __shfl_xor(s, o);
    if (tid == 0) out[0] = (float)s;
}

// ---------------------------------------------------------------------------
extern "C" void kernel_launch(void* const* d_in, const int* in_sizes, int n_in,
                              void* d_out, int out_size, void* d_ws, size_t ws_size,
                              hipStream_t stream)
{
    const int*   feat = (const int*)d_in[0];
    const float* w    = (const float*)d_in[1];
    const float* tr   = (const float*)d_in[2];
    float* out = (float*)d_out;
    char*  ws  = (char*)d_ws;

    float*         em = (float*)(ws + EM_OFF);
    unsigned char* bp = (unsigned char*)(ws + BP_OFF);
    unsigned char* gm = (unsigned char*)(ws + G_OFF);
    int*           bt = (int*)(ws + BT_OFF);
    float*         ae = (float*)(ws + AE_OFF);
    double*        ps = (double*)(ws + PS_OFF);

    k_emissions <<<(T_LEN * LTAG) / 256, 256, 0, stream>>>(feat, w, em);
    k_phase3    <<<NCHUNK, 64, 0, stream>>>(tr, em, bp, gm, ae);
    k_final     <<<1,      64, 0, stream>>>(tr, ae, gm, bt);
    k_path_score<<<NCHUNK, 64, 0, stream>>>(tr, em, bp, bt, out, ps);
    k_sfin      <<<1,      64, 0, stream>>>(ps, out);
}